// Round 4
// baseline (464.101 us; speedup 1.0000x reference)
//
#include <hip/hip_runtime.h>
#include <hip/hip_bf16.h>

// out = conv3x3(upsample2x(x), ternary(W)) + bias
// Per output parity (pa,pb): 2x2 conv on x with effective ternary-sum weights.
// MFMA 16x16x32 bf16. Block = 256co x 128ow x 2 h-rows (pa fixed), 8 waves =
// 4 co-chunks x 2 pb. 3 x-rows ring-buffered in 96KB LDS, staged between
// phases with global_load_lds; A streamed fragment-linear from L2.

using bf16x8 = __attribute__((ext_vector_type(8))) short;
using f32x4  = __attribute__((ext_vector_type(4))) float;

#define MFMA16(a, b, c) __builtin_amdgcn_mfma_f32_16x16x32_bf16(a, b, c, 0, 0, 0)

static __device__ __forceinline__ unsigned short f2bf(float f) {
  union { float f; unsigned u; } v; v.f = f;
  unsigned r = v.u + 0x7fffu + ((v.u >> 16) & 1u);
  return (unsigned short)(r >> 16);
}

static __device__ __forceinline__ void gload_lds16(const void* g, void* l) {
  __builtin_amdgcn_global_load_lds(
      (const __attribute__((address_space(1))) unsigned int*)g,
      (__attribute__((address_space(3))) unsigned int*)l, 16, 0, 0);
}

// ---- prep weights: quantize + 16 effective 256x256 mats, per-wave linear ----
// strides (shorts): fm 512, dw 2048, kqu 4096, wm 32768, pb 131072, (pa*2+dh) 262144
// co = wm*64 + fm*16 + (lane&15); ci = kqu*32 + (lane>>4)*8 + e
__global__ void prep_w_kernel(const float* __restrict__ w,
                              unsigned short* __restrict__ wqf) {
  int t = blockIdx.x * 256 + threadIdx.x;   // one (co,ci) per thread
  int co = t >> 8, ci = t & 255;
  const float* wp = w + (size_t)(co * 256 + ci) * 9;
  float q[3][3];
#pragma unroll
  for (int kh = 0; kh < 3; ++kh)
#pragma unroll
    for (int kw = 0; kw < 3; ++kw) {
      float x = wp[kh * 3 + kw];
      q[kh][kw] = (x > 0.001f) ? 1.0f : ((x < -0.001f) ? -1.0f : 0.0f);
    }
  int wm = co >> 6, fm = (co >> 4) & 3;
  int kqu = ci >> 5;
  int lane = (co & 15) | (((ci >> 3) & 3) << 4);
  int e = ci & 7;
#pragma unroll
  for (int pa = 0; pa < 2; ++pa)
#pragma unroll
    for (int pb = 0; pb < 2; ++pb)
#pragma unroll
      for (int dh = 0; dh < 2; ++dh)
#pragma unroll
        for (int dw = 0; dw < 2; ++dw) {
          int h0 = dh * (1 + pa), h1 = dh ? 3 : (1 + pa);
          int w0 = dw * (1 + pb), w1 = dw ? 3 : (1 + pb);
          float s = 0.f;
          for (int kh = h0; kh < h1; ++kh)
            for (int kw = w0; kw < w1; ++kw) s += q[kh][kw];
          size_t idx = (size_t)(pa * 2 + dh) * 262144 + (size_t)pb * 131072 +
                       (size_t)wm * 32768 + (size_t)kqu * 4096 +
                       (size_t)dw * 2048 + (size_t)fm * 512 + lane * 8 + e;
          wqf[idx] = f2bf(s);
        }
}

// ---- transpose x (fp32 NCHW) -> xT bf16 [b][h][w][ci] ----------------------
__global__ void xpose_kernel(const float* __restrict__ x,
                             unsigned short* __restrict__ xT) {
  __shared__ __align__(16) unsigned short tile[64][72];
  int idx = blockIdx.x;                 // 16*64*4 blocks
  int cb = idx & 3, h = (idx >> 2) & 63, b = idx >> 8;
  int t = threadIdx.x;
  int ci_l = t >> 2, wseg = (t & 3) * 16;
  const float* src = x + ((size_t)((b * 256 + cb * 64 + ci_l) * 64 + h) * 64 + wseg);
#pragma unroll
  for (int j = 0; j < 16; ++j) tile[ci_l][wseg + j] = f2bf(src[j]);
  __syncthreads();
  int w_l = t >> 2, seg = t & 3;
  unsigned short* dst = xT + ((size_t)((b * 64 + h) * 64 + w_l) * 256 + cb * 64 + seg * 16);
  bf16x8 o0, o1;
#pragma unroll
  for (int j = 0; j < 8; ++j) o0[j] = (short)tile[seg * 16 + j][w_l];
#pragma unroll
  for (int j = 0; j < 8; ++j) o1[j] = (short)tile[seg * 16 + 8 + j][w_l];
  *(bf16x8*)dst = o0;
  *(bf16x8*)(dst + 8) = o1;
}

// ---- main conv GEMM --------------------------------------------------------
__launch_bounds__(512, 2)
__global__ void conv_kernel(const unsigned short* __restrict__ xT,
                            const unsigned short* __restrict__ wqf,
                            const float* __restrict__ bias,
                            float* __restrict__ out) {
  // 3 row-slots: slot*32768 + cik*8192 + col*128 + seg*16 (seg XOR-swizzled)
  __shared__ __align__(16) unsigned char Bs[3 * 32768];   // 96 KB

  int bid = blockIdx.x;
  int idx = (bid & 7) * 64 + (bid >> 3);    // bijective XCD swizzle (512%8==0)
  int pa = idx & 1;
  int hg = (idx >> 1) & 15;                 // h0 = hg*4, block covers h0..h0+3
  int bb = idx >> 5;
  int h0 = hg * 4;

  int t = threadIdx.x;
  int lane = t & 63, wid = t >> 6;
  int wm = wid >> 1, pb = wid & 1;
  int lr = lane & 15, l4 = lane >> 4;

  // staging source (inverse swizzle on global side, rule #21)
  int colS = t >> 3;
  int segL = (t & 7) ^ (colS & 7);
  const unsigned short* gsrc =
      xT + ((size_t)bb * 64 * 64 + colS) * 256 + segL * 8;

#define STAGE(row, slot)                                                      \
  do {                                                                        \
    if ((row) >= 0 && (row) < 64) {                                           \
      const unsigned short* g_ = gsrc + (size_t)(row) * 16384;                \
      _Pragma("unroll")                                                       \
      for (int ck_ = 0; ck_ < 4; ++ck_)                                       \
        gload_lds16(g_ + ck_ * 64, Bs + (slot) * 32768 + ck_ * 8192 + wid * 1024); \
    } else {                                                                  \
      const bf16x8 z_ = {0, 0, 0, 0, 0, 0, 0, 0};                             \
      _Pragma("unroll")                                                       \
      for (int ck_ = 0; ck_ < 4; ++ck_)                                       \
        *(bf16x8*)(Bs + (slot) * 32768 + ck_ * 8192 + t * 16) = z_;           \
    }                                                                         \
  } while (0)

  // prologue: rows h0-1+pa, h0+pa, h0+1+pa -> slots 0,1,2
  STAGE(h0 - 1 + pa, 0);
  STAGE(h0 + pa, 1);
  STAGE(h0 + 1 + pa, 2);

  // per-thread LDS read offsets
  int colb[2][4], sego[2][2];
#pragma unroll
  for (int dw = 0; dw < 2; ++dw) {
    int sh = pb + dw - 1;
#pragma unroll
    for (int fn = 0; fn < 4; ++fn)
      colb[dw][fn] = (((fn * 16 + lr + sh) & 63) << 7);
#pragma unroll
    for (int kq = 0; kq < 2; ++kq)
      sego[kq][dw] = (((kq * 4 + l4) ^ ((lr + sh) & 7)) << 4);
  }
  bool zlo = (pb == 0) && (lr == 0);    // dw0,fn0 reads w=-1
  bool zhi = (pb == 1) && (lr == 15);   // dw1,fn3 reads w=64

  const unsigned short* a0 =
      wqf + (size_t)(pa * 2) * 262144 + (size_t)pb * 131072 +
      (size_t)wm * 32768 + lane * 8;
  const unsigned short* a1 = a0 + 262144;   // dh=1

  float bcache[4][4];
#pragma unroll
  for (int fm = 0; fm < 4; ++fm)
#pragma unroll
    for (int i = 0; i < 4; ++i) bcache[fm][i] = bias[wm * 64 + fm * 16 + l4 * 4 + i];

  f32x4 acc[2][4][4];                   // [hr][fm][fn]
#pragma unroll
  for (int r = 0; r < 2; ++r)
#pragma unroll
    for (int m = 0; m < 4; ++m)
#pragma unroll
      for (int n = 0; n < 4; ++n) acc[r][m][n] = (f32x4){0.f, 0.f, 0.f, 0.f};

  const bf16x8 zfr = {0, 0, 0, 0, 0, 0, 0, 0};

  // PHASE(dh): hr0 reads slot sA, hr1 reads slot sB; A shared across hr.
#define PHASE(APTR, sA, sB)                                                   \
  do {                                                                        \
    _Pragma("unroll")                                                         \
    for (int cik = 0; cik < 4; ++cik) {                                       \
      _Pragma("unroll")                                                       \
      for (int kq = 0; kq < 2; ++kq) {                                        \
        const unsigned short* au = (APTR) + (cik * 2 + kq) * 4096;            \
        bf16x8 a[2][4];                                                       \
        _Pragma("unroll")                                                     \
        for (int dw = 0; dw < 2; ++dw)                                        \
          _Pragma("unroll")                                                   \
          for (int fm = 0; fm < 4; ++fm)                                      \
            a[dw][fm] = *(const bf16x8*)(au + dw * 2048 + fm * 512);          \
        _Pragma("unroll")                                                     \
        for (int hr = 0; hr < 2; ++hr) {                                      \
          const unsigned char* bbase =                                        \
              Bs + (hr ? (sB) : (sA)) * 32768 + cik * 8192;                   \
          _Pragma("unroll")                                                   \
          for (int dw = 0; dw < 2; ++dw) {                                    \
            bf16x8 bf[4];                                                     \
            _Pragma("unroll")                                                 \
            for (int fn = 0; fn < 4; ++fn)                                    \
              bf[fn] = *(const bf16x8*)(bbase + colb[dw][fn] + sego[kq][dw]); \
            if (dw == 0 && zlo) bf[0] = zfr;                                  \
            if (dw == 1 && zhi) bf[3] = zfr;                                  \
            _Pragma("unroll")                                                 \
            for (int fm = 0; fm < 4; ++fm)                                    \
              _Pragma("unroll")                                               \
              for (int fn = 0; fn < 4; ++fn)                                  \
                acc[hr][fm][fn] = MFMA16(a[dw][fm], bf[fn], acc[hr][fm][fn]); \
          }                                                                   \
        }                                                                     \
      }                                                                       \
    }                                                                         \
  } while (0)

#define EPILOGUE(hbase)                                                       \
  do {                                                                        \
    _Pragma("unroll")                                                         \
    for (int hr = 0; hr < 2; ++hr) {                                          \
      int oh = 2 * ((hbase) + hr) + pa;                                       \
      _Pragma("unroll")                                                       \
      for (int fm = 0; fm < 4; ++fm)                                          \
        _Pragma("unroll")                                                     \
        for (int i = 0; i < 4; ++i) {                                         \
          int co = wm * 64 + fm * 16 + l4 * 4 + i;                            \
          float* orow = out + ((size_t)(bb * 256 + co) * 128 + oh) * 128 + pb; \
          _Pragma("unroll")                                                   \
          for (int fn = 0; fn < 4; ++fn)                                      \
            orow[2 * (fn * 16 + lr)] = acc[hr][fm][fn][i] + bcache[fm][i];    \
        }                                                                     \
    }                                                                         \
  } while (0)

  // ---- iter 0: h = h0; rows (h0-1+pa, h0+pa, h0+1+pa) in slots (0,1,2) ----
  __syncthreads();                      // prologue staging complete
  PHASE(a0, 0, 1);                      // dh=0: hr0<-slot0, hr1<-slot1
  __syncthreads();                      // slot0 readers done
  STAGE(h0 + 2 + pa, 0);                // iter1 row r3 -> slot0
  PHASE(a1, 1, 2);                      // dh=1: hr0<-slot1, hr1<-slot2
  __syncthreads();                      // slot1 readers done; drains G1 too
  STAGE(h0 + 3 + pa, 1);                // iter1 row r4 -> slot1
  EPILOGUE(h0);
#pragma unroll
  for (int r = 0; r < 2; ++r)
#pragma unroll
    for (int m = 0; m < 4; ++m)
#pragma unroll
      for (int n = 0; n < 4; ++n) acc[r][m][n] = (f32x4){0.f, 0.f, 0.f, 0.f};
  __syncthreads();                      // drains G2; all staging landed

  // ---- iter 1: h = h0+2; rows in slots (2,0,1) ----
  PHASE(a0, 2, 0);                      // dh=0: hr0<-slot2, hr1<-slot0
  PHASE(a1, 0, 1);                      // dh=1: hr0<-slot0, hr1<-slot1
  EPILOGUE(h0 + 2);

#undef STAGE
#undef PHASE
#undef EPILOGUE
}

// ---- fallback (ws too small): naive direct conv ----------------------------
__global__ void fallback_kernel(const float* __restrict__ x,
                                const float* __restrict__ w,
                                const float* __restrict__ bias,
                                float* __restrict__ out, long total) {
  long i = (long)blockIdx.x * 256 + threadIdx.x;
  if (i >= total) return;
  int ow = i & 127; int oh = (int)((i >> 7) & 127);
  int co = (int)((i >> 14) & 255); int bb = (int)(i >> 22);
  float s = bias[co];
  for (int ci = 0; ci < 256; ++ci) {
    for (int kh = 0; kh < 3; ++kh) {
      int r = oh - 1 + kh;
      if (r < 0 || r > 127) continue;
      for (int kw = 0; kw < 3; ++kw) {
        int c = ow - 1 + kw;
        if (c < 0 || c > 127) continue;
        float wv = w[((co * 256 + ci) * 3 + kh) * 3 + kw];
        float q = (wv > 0.001f) ? 1.f : ((wv < -0.001f) ? -1.f : 0.f);
        s += q * x[((size_t)(bb * 256 + ci) * 64 + (r >> 1)) * 64 + (c >> 1)];
      }
    }
  }
  out[i] = s;
}

extern "C" void kernel_launch(void* const* d_in, const int* in_sizes, int n_in,
                              void* d_out, int out_size, void* d_ws, size_t ws_size,
                              hipStream_t stream) {
  const float* x    = (const float*)d_in[0];
  const float* wt   = (const float*)d_in[3];
  const float* bias = (const float*)d_in[4];
  float* out = (float*)d_out;

  size_t need = (size_t)2 * 1024 * 1024 + (size_t)16777216 * 2;
  if (ws_size < need) {
    long total = 67108864;
    fallback_kernel<<<(int)((total + 255) / 256), 256, 0, stream>>>(x, wt, bias, out, total);
    return;
  }
  unsigned short* wqf = (unsigned short*)d_ws;
  unsigned short* xT  = (unsigned short*)((char*)d_ws + 2 * 1024 * 1024);

  prep_w_kernel<<<256, 256, 0, stream>>>(wt, wqf);
  xpose_kernel<<<4096, 256, 0, stream>>>(x, xT);
  conv_kernel<<<512, 512, 0, stream>>>(xT, wqf, bias, out);
}

// Round 5
// 203.038 us; speedup vs baseline: 2.2858x; 2.2858x over previous
//
#include <hip/hip_runtime.h>
#include <hip/hip_bf16.h>

// out = conv3x3(upsample2x(x), ternary(W)) + bias
// Per output parity (pa,pb): 2x2 conv on x with effective ternary-sum weights.
// MFMA 16x16x32 bf16. Block = 256 thr (4 waves), tile 256co x 128ow x 1 h-row,
// pb folded in-thread (float2 stores). Wave = 64co(fm4) x 64col(fn4) x 2pb.
// 2 x-rows staged once into 64KB LDS (XOR-swizzled), ONE barrier, then an
// unbroken 1024-MFMA stream per wave. A streamed fragment-linear from L2.

using bf16x8 = __attribute__((ext_vector_type(8))) short;
using f32x4  = __attribute__((ext_vector_type(4))) float;

#define MFMA16(a, b, c) __builtin_amdgcn_mfma_f32_16x16x32_bf16(a, b, c, 0, 0, 0)

static __device__ __forceinline__ unsigned short f2bf(float f) {
  union { float f; unsigned u; } v; v.f = f;
  unsigned r = v.u + 0x7fffu + ((v.u >> 16) & 1u);
  return (unsigned short)(r >> 16);
}

static __device__ __forceinline__ void gload_lds16(const void* g, void* l) {
  __builtin_amdgcn_global_load_lds(
      (const __attribute__((address_space(1))) unsigned int*)g,
      (__attribute__((address_space(3))) unsigned int*)l, 16, 0, 0);
}

// ---- prep weights: quantize + 16 effective 256x256 mats, fragment-linear ----
// strides (shorts): fm 512, dw 2048, kqu 4096, wm 32768, pb 131072, (pa*2+dh) 262144
// co = wm*64 + fm*16 + (lane&15); ci = kqu*32 + (lane>>4)*8 + e
__global__ void prep_w_kernel(const float* __restrict__ w,
                              unsigned short* __restrict__ wqf) {
  int t = blockIdx.x * 256 + threadIdx.x;   // one (co,ci) per thread
  int co = t >> 8, ci = t & 255;
  const float* wp = w + (size_t)(co * 256 + ci) * 9;
  float q[3][3];
#pragma unroll
  for (int kh = 0; kh < 3; ++kh)
#pragma unroll
    for (int kw = 0; kw < 3; ++kw) {
      float x = wp[kh * 3 + kw];
      q[kh][kw] = (x > 0.001f) ? 1.0f : ((x < -0.001f) ? -1.0f : 0.0f);
    }
  int wm = co >> 6, fm = (co >> 4) & 3;
  int kqu = ci >> 5;
  int lane = (co & 15) | (((ci >> 3) & 3) << 4);
  int e = ci & 7;
#pragma unroll
  for (int pa = 0; pa < 2; ++pa)
#pragma unroll
    for (int pb = 0; pb < 2; ++pb)
#pragma unroll
      for (int dh = 0; dh < 2; ++dh)
#pragma unroll
        for (int dw = 0; dw < 2; ++dw) {
          int h0 = dh * (1 + pa), h1 = dh ? 3 : (1 + pa);
          int w0 = dw * (1 + pb), w1 = dw ? 3 : (1 + pb);
          float s = 0.f;
          for (int kh = h0; kh < h1; ++kh)
            for (int kw = w0; kw < w1; ++kw) s += q[kh][kw];
          size_t idx = (size_t)(pa * 2 + dh) * 262144 + (size_t)pb * 131072 +
                       (size_t)wm * 32768 + (size_t)kqu * 4096 +
                       (size_t)dw * 2048 + (size_t)fm * 512 + lane * 8 + e;
          wqf[idx] = f2bf(s);
        }
}

// ---- transpose x (fp32 NCHW) -> xT bf16 [b][h][w][ci] ----------------------
__global__ void xpose_kernel(const float* __restrict__ x,
                             unsigned short* __restrict__ xT) {
  __shared__ __align__(16) unsigned short tile[64][72];
  int idx = blockIdx.x;                 // 16*64*4 blocks
  int cb = idx & 3, h = (idx >> 2) & 63, b = idx >> 8;
  int t = threadIdx.x;
  int ci_l = t >> 2, wseg = (t & 3) * 16;
  const float* src = x + ((size_t)((b * 256 + cb * 64 + ci_l) * 64 + h) * 64 + wseg);
#pragma unroll
  for (int j = 0; j < 16; ++j) tile[ci_l][wseg + j] = f2bf(src[j]);
  __syncthreads();
  int w_l = t >> 2, seg = t & 3;
  unsigned short* dst = xT + ((size_t)((b * 64 + h) * 64 + w_l) * 256 + cb * 64 + seg * 16);
  bf16x8 o0, o1;
#pragma unroll
  for (int j = 0; j < 8; ++j) o0[j] = (short)tile[seg * 16 + j][w_l];
#pragma unroll
  for (int j = 0; j < 8; ++j) o1[j] = (short)tile[seg * 16 + 8 + j][w_l];
  *(bf16x8*)dst = o0;
  *(bf16x8*)(dst + 8) = o1;
}

// ---- main conv GEMM --------------------------------------------------------
__launch_bounds__(256, 2)
__global__ void conv_kernel(const unsigned short* __restrict__ xT,
                            const unsigned short* __restrict__ wqf,
                            const float* __restrict__ bias,
                            float* __restrict__ out) {
  // 2 row-slots: dh*32768 + cik*8192 + col*128 + seg*16 (seg XOR-swizzled)
  __shared__ __align__(16) unsigned char Bs[2 * 32768];   // 64 KB

  int bid = blockIdx.x;
  int idx = (bid & 7) * 256 + (bid >> 3);   // bijective XCD swizzle (2048%8==0)
  int pa = idx & 1;
  int h  = (idx >> 1) & 63;
  int bb = idx >> 7;

  int t = threadIdx.x;                      // 256 threads, 4 waves
  int lane = t & 63, wm = t >> 6;
  int lr = lane & 15, l4 = lane >> 4;

  // ---- stage 2 rows (source-side inverse swizzle, rule #21) ----
  {
    // round r, wave w, lane l -> col = r*32 + w*8 + (l>>3), physical seg = l&7
    // logical seg for that slot = (l&7) ^ (col&7) = (l&7) ^ ((l>>3)&7)
    int colR0 = wm * 8 + (lane >> 3);       // col for r=0 (r=1 adds 32)
    int segL = (lane & 7) ^ ((lane >> 3) & 7);
    const unsigned short* g0 =
        xT + ((size_t)bb * 64 * 64 + colR0) * 256 + segL * 8;
#pragma unroll
    for (int dh = 0; dh < 2; ++dh) {
      int row = h - 1 + pa + dh;
      if (row >= 0 && row < 64) {
        const unsigned short* grow = g0 + (size_t)row * 16384;
#pragma unroll
        for (int cik = 0; cik < 4; ++cik)
#pragma unroll
          for (int r = 0; r < 2; ++r)
            gload_lds16(grow + r * 32 * 256 + cik * 64,
                        Bs + dh * 32768 + cik * 8192 + r * 4096 + wm * 1024);
      } else {
        const bf16x8 z_ = {0, 0, 0, 0, 0, 0, 0, 0};
#pragma unroll
        for (int j = 0; j < 8; ++j)
          *(bf16x8*)(Bs + dh * 32768 + t * 128 + j * 16) = z_;
      }
    }
  }

  // per-thread LDS read offsets; s3 = pb+dw (shift = s3-1)
  int colb3[3][4], sego3[2][3];
#pragma unroll
  for (int s3 = 0; s3 < 3; ++s3) {
#pragma unroll
    for (int fn = 0; fn < 4; ++fn)
      colb3[s3][fn] = (((fn * 16 + lr + s3 - 1) & 63) << 7);
#pragma unroll
    for (int kq = 0; kq < 2; ++kq)
      sego3[kq][s3] = (((kq * 4 + l4) ^ ((lr + s3 - 1) & 7)) << 4);
  }
  bool zlo = (lr == 0);    // s3=0, fn=0 reads w=-1
  bool zhi = (lr == 15);   // s3=2, fn=3 reads w=64
  const bf16x8 zfr = {0, 0, 0, 0, 0, 0, 0, 0};

  f32x4 acc[2][4][4];      // [pb][fm][fn]
#pragma unroll
  for (int p = 0; p < 2; ++p)
#pragma unroll
    for (int m = 0; m < 4; ++m)
#pragma unroll
      for (int n = 0; n < 4; ++n) acc[p][m][n] = (f32x4){0.f, 0.f, 0.f, 0.f};

  const unsigned short* abase =
      wqf + (size_t)(pa * 2) * 262144 + (size_t)wm * 32768 + lane * 8;

  __syncthreads();         // all staging resident

#pragma unroll
  for (int dh = 0; dh < 2; ++dh) {
    const unsigned short* adh = abase + (size_t)dh * 262144;
    const unsigned char* bdh = Bs + dh * 32768;
#pragma unroll
    for (int cik = 0; cik < 4; ++cik) {
      const unsigned char* bc = bdh + cik * 8192;
#pragma unroll
      for (int kq = 0; kq < 2; ++kq) {
        const unsigned short* au = adh + (cik * 2 + kq) * 4096;
#pragma unroll
        for (int s3 = 0; s3 < 3; ++s3) {
          bf16x8 bf[4];
#pragma unroll
          for (int fn = 0; fn < 4; ++fn)
            bf[fn] = *(const bf16x8*)(bc + colb3[s3][fn] + sego3[kq][s3]);
          if (s3 == 0 && zlo) bf[0] = zfr;
          if (s3 == 2 && zhi) bf[3] = zfr;
          // mats with pb+dw == s3
#pragma unroll
          for (int pb = 0; pb < 2; ++pb) {
            int dw = s3 - pb;
            if (dw < 0 || dw > 1) continue;
            const unsigned short* am = au + pb * 131072 + dw * 2048;
            bf16x8 a[4];
#pragma unroll
            for (int fm = 0; fm < 4; ++fm)
              a[fm] = *(const bf16x8*)(am + fm * 512);
#pragma unroll
            for (int fm = 0; fm < 4; ++fm)
#pragma unroll
              for (int fn = 0; fn < 4; ++fn)
                acc[pb][fm][fn] = MFMA16(a[fm], bf[fn], acc[pb][fm][fn]);
          }
        }
      }
    }
  }

  // ---- epilogue: pb-interleaved float2 stores (fully coalesced) ----
  int oh = 2 * h + pa;
#pragma unroll
  for (int fm = 0; fm < 4; ++fm) {
#pragma unroll
    for (int i = 0; i < 4; ++i) {
      int co = wm * 64 + fm * 16 + l4 * 4 + i;
      float bi = bias[co];
      float* orow = out + ((size_t)(bb * 256 + co) * 128 + oh) * 128;
#pragma unroll
      for (int fn = 0; fn < 4; ++fn) {
        int ww = fn * 16 + lr;
        *(float2*)(orow + 2 * ww) =
            make_float2(acc[0][fm][fn][i] + bi, acc[1][fm][fn][i] + bi);
      }
    }
  }
}

// ---- fallback (ws too small): naive direct conv ----------------------------
__global__ void fallback_kernel(const float* __restrict__ x,
                                const float* __restrict__ w,
                                const float* __restrict__ bias,
                                float* __restrict__ out, long total) {
  long i = (long)blockIdx.x * 256 + threadIdx.x;
  if (i >= total) return;
  int ow = i & 127; int oh = (int)((i >> 7) & 127);
  int co = (int)((i >> 14) & 255); int bb = (int)(i >> 22);
  float s = bias[co];
  for (int ci = 0; ci < 256; ++ci) {
    for (int kh = 0; kh < 3; ++kh) {
      int r = oh - 1 + kh;
      if (r < 0 || r > 127) continue;
      for (int kw = 0; kw < 3; ++kw) {
        int c = ow - 1 + kw;
        if (c < 0 || c > 127) continue;
        float wv = w[((co * 256 + ci) * 3 + kh) * 3 + kw];
        float q = (wv > 0.001f) ? 1.f : ((wv < -0.001f) ? -1.f : 0.f);
        s += q * x[((size_t)(bb * 256 + ci) * 64 + (r >> 1)) * 64 + (c >> 1)];
      }
    }
  }
  out[i] = s;
}

extern "C" void kernel_launch(void* const* d_in, const int* in_sizes, int n_in,
                              void* d_out, int out_size, void* d_ws, size_t ws_size,
                              hipStream_t stream) {
  const float* x    = (const float*)d_in[0];
  const float* wt   = (const float*)d_in[3];
  const float* bias = (const float*)d_in[4];
  float* out = (float*)d_out;

  size_t need = (size_t)2 * 1024 * 1024 + (size_t)16777216 * 2;
  if (ws_size < need) {
    long total = 67108864;
    fallback_kernel<<<(int)((total + 255) / 256), 256, 0, stream>>>(x, wt, bias, out, total);
    return;
  }
  unsigned short* wqf = (unsigned short*)d_ws;
  unsigned short* xT  = (unsigned short*)((char*)d_ws + 2 * 1024 * 1024);

  prep_w_kernel<<<256, 256, 0, stream>>>(wt, wqf);
  xpose_kernel<<<4096, 256, 0, stream>>>(x, xT);
  conv_kernel<<<2048, 256, 0, stream>>>(xT, wqf, bias, out);
}